// Round 2
// 1131.437 us; speedup vs baseline: 1.1023x; 1.1023x over previous
//
#include <hip/hip_runtime.h>
#include <hip/hip_bf16.h>

// Problem constants (from reference): B=8, TS=32, L=1025, D=512, WIN=2
// m has M = 8*32*513 = 131328 rows of F = 1024 features.
#define L_SEQ 1025
#define D_MODEL 512
#define KDIM 1024
#define NDIM 512
#define BM 32
#define M_ROWS 131328

typedef __bf16 bf16x4 __attribute__((ext_vector_type(4)));
typedef __bf16 bf16x8 __attribute__((ext_vector_type(8)));
typedef float f32x4 __attribute__((ext_vector_type(4)));

// lin_w is [K=1024][N=512] fp32 -> Bt bf16 [N=512][K=1024] (n-major) in ws.
// LDS tile transpose: coalesced reads (row of lin_w) and writes (row of Bt).
__global__ __launch_bounds__(256)
void prep_b_kernel(const float* __restrict__ lin_w, __bf16* __restrict__ Bt) {
    __shared__ float tile[64][65];
    const int bk = (blockIdx.x & 15) * 64;   // 1024/64 = 16 k-tiles
    const int bn = (blockIdx.x >> 4) * 64;   // 512/64  = 8  n-tiles
    const int c = threadIdx.x & 63;
    const int r0 = threadIdx.x >> 6;         // 0..3
    #pragma unroll
    for (int i = 0; i < 16; ++i) {
        const int r = r0 * 16 + i;
        tile[r][c] = lin_w[(size_t)(bk + r) * NDIM + bn + c];
    }
    __syncthreads();
    #pragma unroll
    for (int i = 0; i < 16; ++i) {
        const int n = r0 * 16 + i;
        Bt[(size_t)(bn + n) * KDIM + bk + c] = (__bf16)tile[c][n];
    }
}

__global__ __launch_bounds__(512, 4)
void fused_ln_gemm_kernel(const float* __restrict__ x,
                          const float* __restrict__ norm_w,
                          const float* __restrict__ norm_b,
                          const __bf16* __restrict__ Bt,
                          const float* __restrict__ lin_b,
                          float* __restrict__ out) {
    // A tile in LDS, bf16, layout [kc=k/8][m][j=k%8] with XOR swizzle on m:
    // idx(kc,m,j) = (kc*32 + (m ^ (kc&31)))*8 + j   -- 64 KiB exactly.
    __shared__ __bf16 Alds[BM * KDIM];
    static_assert(sizeof(__bf16) * BM * KDIM == 65536, "LDS must stay 64 KiB");

    const int t = threadIdx.x;
    const int g0 = blockIdx.x * BM;
    const int lane = t & 63;
    const int wave = t >> 6;

    // ---------------- Phase 1: gather + LayerNorm -> LDS (bf16) -------------
    // Each wave owns 4 rows; a full wave (64 lanes x 16 floats) per row.
    // All 16 loads per thread are issued before any reduction (one latency
    // exposure), then 4 independent shfl-reduce chains run with ILP.
    {
        const int kb = lane * 4;             // lane's base k within each 256-chunk
        f32x4 v[4][4];
        float sum[4], ssq[4];

        #pragma unroll
        for (int rr = 0; rr < 4; ++rr) {
            const int g = g0 + wave * 4 + rr;
            const int b_ts = g / 513;
            const int s = g - b_ts * 513;
            const float* xb = x + (size_t)b_ts * (L_SEQ * D_MODEL);
            const int l0 = s ? (2 * s - 1) : 0;
            const int l1 = s ? (2 * s) : 0;
            const float* p0 = xb + (size_t)l0 * D_MODEL + kb;
            const float* p1 = xb + (size_t)l1 * D_MODEL + kb;
            sum[rr] = 0.f; ssq[rr] = 0.f;
            #pragma unroll
            for (int i = 0; i < 4; ++i) {
                const float* p = (i < 2) ? (p0 + i * 256) : (p1 + (i - 2) * 256);
                v[rr][i] = *(const f32x4*)p;
                #pragma unroll
                for (int q = 0; q < 4; ++q) {
                    sum[rr] += v[rr][i][q];
                    ssq[rr] += v[rr][i][q] * v[rr][i][q];
                }
            }
        }

        // wave-wide reduce, 4 rows interleaved for ILP
        #pragma unroll
        for (int off = 32; off >= 1; off >>= 1) {
            #pragma unroll
            for (int rr = 0; rr < 4; ++rr) {
                sum[rr] += __shfl_xor(sum[rr], off);
                ssq[rr] += __shfl_xor(ssq[rr], off);
            }
        }

        float mu[4], rs[4];
        #pragma unroll
        for (int rr = 0; rr < 4; ++rr) {
            mu[rr] = sum[rr] * (1.f / 1024.f);
            const float var = ssq[rr] * (1.f / 1024.f) - mu[rr] * mu[rr];
            rs[rr] = rsqrtf(var + 1e-5f);
        }

        #pragma unroll
        for (int i = 0; i < 4; ++i) {
            const int k = i * 256 + kb;
            const f32x4 w4 = *(const f32x4*)(norm_w + k);
            const f32x4 b4 = *(const f32x4*)(norm_b + k);
            const int kc = k >> 3;           // i*32 + (lane>>1)
            const int j = k & 7;             // (lane&1)*4
            const int rot = kc & 31;
            #pragma unroll
            for (int rr = 0; rr < 4; ++rr) {
                const int r = wave * 4 + rr;
                bf16x4 o;
                #pragma unroll
                for (int q = 0; q < 4; ++q)
                    o[q] = (__bf16)((v[rr][i][q] - mu[rr]) * rs[rr] * w4[q] + b4[q]);
                const int row = r ^ rot;     // swizzle
                *(bf16x4*)&Alds[(kc * 32 + row) * 8 + j] = o;
            }
        }
    }
    __syncthreads();

    // ---------------- Phase 2: bf16 MFMA GEMM (32 x 512 per block) ----------
    // 8 waves x 64 output cols each; 4 Bt loads per K-iter per wave.
    const int col = lane & 15;
    const int quad = lane >> 4;
    const int n0 = wave * 64;

    f32x4 acc[2][4] = {};
    const __bf16* bbase = Bt + (size_t)(n0 + col) * KDIM + quad * 8;

    #pragma unroll 4
    for (int ks = 0; ks < KDIM; ks += 32) {
        const int kc = (ks >> 3) + quad;
        const int rot = kc & 31;
        bf16x8 a0 = *(const bf16x8*)&Alds[(kc * 32 + (col ^ rot)) * 8];
        bf16x8 a1 = *(const bf16x8*)&Alds[(kc * 32 + ((16 + col) ^ rot)) * 8];
        #pragma unroll
        for (int nt = 0; nt < 4; ++nt) {
            bf16x8 b = *(const bf16x8*)(bbase + nt * (16 * KDIM) + ks);
            acc[0][nt] = __builtin_amdgcn_mfma_f32_16x16x32_bf16(a0, b, acc[0][nt], 0, 0, 0);
            acc[1][nt] = __builtin_amdgcn_mfma_f32_16x16x32_bf16(a1, b, acc[1][nt], 0, 0, 0);
        }
    }

    // ---------------- Epilogue: + lin_b, nontemporal fp32 store -------------
    #pragma unroll
    for (int nt = 0; nt < 4; ++nt) {
        const int n = n0 + nt * 16 + col;
        const float bias = lin_b[n];
        #pragma unroll
        for (int mt = 0; mt < 2; ++mt) {
            const int row = g0 + mt * 16 + quad * 4;
            #pragma unroll
            for (int rg = 0; rg < 4; ++rg) {
                __builtin_nontemporal_store(acc[mt][nt][rg] + bias,
                                            &out[(size_t)(row + rg) * NDIM + n]);
            }
        }
    }
}

extern "C" void kernel_launch(void* const* d_in, const int* in_sizes, int n_in,
                              void* d_out, int out_size, void* d_ws, size_t ws_size,
                              hipStream_t stream) {
    const float* x      = (const float*)d_in[0];
    const float* norm_w = (const float*)d_in[1];
    const float* norm_b = (const float*)d_in[2];
    const float* lin_w  = (const float*)d_in[3];
    const float* lin_b  = (const float*)d_in[4];
    float* out = (float*)d_out;
    __bf16* Bt = (__bf16*)d_ws;   // 512*1024*2 = 1 MiB

    prep_b_kernel<<<128, 256, 0, stream>>>(lin_w, Bt);
    fused_ln_gemm_kernel<<<M_ROWS / BM, 512, 0, stream>>>(x, norm_w, norm_b, Bt, lin_b, out);
}

// Round 3
// 892.738 us; speedup vs baseline: 1.3971x; 1.2674x over previous
//
#include <hip/hip_runtime.h>
#include <hip/hip_bf16.h>

// Problem constants (from reference): B=8, TS=32, L=1025, D=512, WIN=2
// m has M = 8*32*513 = 131328 rows of F = 1024 features.
#define L_SEQ 1025
#define D_MODEL 512
#define KDIM 1024
#define NDIM 512
#define BM 32
#define M_ROWS 131328

typedef __bf16 bf16x4 __attribute__((ext_vector_type(4)));
typedef __bf16 bf16x8 __attribute__((ext_vector_type(8)));
typedef float f32x4 __attribute__((ext_vector_type(4)));

// lin_w is [K=1024][N=512] fp32 -> Bp bf16 in MFMA-FRAGMENT order:
//   chunk c = (n_tile*32 + kk)*64 + lane   (n_tile=n/16, kk=k/32, lane 0..63)
//   element j of chunk: k = kk*32 + (lane>>4)*8 + j,  n = n_tile*16 + (lane&15)
// A wave's B-load for (n_tile, kk) is then 64 lanes x 16B CONTIGUOUS = 1 KiB
// (8 full 128B lines/instr instead of 16 partial 64B segments).
__global__ __launch_bounds__(256)
void prep_b_kernel(const float* __restrict__ lin_w, __bf16* __restrict__ Bp) {
    const int c = blockIdx.x * 256 + threadIdx.x;   // 0 .. 65535 chunks
    const int lane = c & 63;
    const int kk = (c >> 6) & 31;
    const int n_tile = c >> 11;                     // 0..31
    const int col = lane & 15;
    const int quad = lane >> 4;
    const int n = n_tile * 16 + col;
    const int kbase = kk * 32 + quad * 8;
    bf16x8 o;
    #pragma unroll
    for (int j = 0; j < 8; ++j)
        o[j] = (__bf16)lin_w[(size_t)(kbase + j) * NDIM + n];
    *(bf16x8*)&Bp[(size_t)c * 8] = o;
}

__global__ __launch_bounds__(512, 4)
void fused_ln_gemm_kernel(const float* __restrict__ x,
                          const float* __restrict__ norm_w,
                          const float* __restrict__ norm_b,
                          const __bf16* __restrict__ Bp,
                          const float* __restrict__ lin_b,
                          float* __restrict__ out) {
    // A tile in LDS, bf16, layout [kc=k/8][m][j=k%8] with XOR swizzle on m:
    // idx(kc,m,j) = (kc*32 + (m ^ (kc&31)))*8 + j   -- 64 KiB exactly.
    __shared__ __bf16 Alds[BM * KDIM];
    static_assert(sizeof(__bf16) * BM * KDIM == 65536, "LDS must stay 64 KiB");

    const int t = threadIdx.x;
    const int g0 = blockIdx.x * BM;
    const int lane = t & 63;
    const int wave = t >> 6;

    // ---------------- Phase 1: gather + LayerNorm -> LDS (bf16) -------------
    // Each wave owns 4 rows; a full wave (64 lanes x 16 floats) per row.
    {
        const int kb = lane * 4;             // lane's base k within each 256-chunk
        f32x4 v[4][4];
        float sum[4], ssq[4];

        #pragma unroll
        for (int rr = 0; rr < 4; ++rr) {
            const int g = g0 + wave * 4 + rr;
            const int b_ts = g / 513;
            const int s = g - b_ts * 513;
            const float* xb = x + (size_t)b_ts * (L_SEQ * D_MODEL);
            const int l0 = s ? (2 * s - 1) : 0;
            const int l1 = s ? (2 * s) : 0;
            const float* p0 = xb + (size_t)l0 * D_MODEL + kb;
            const float* p1 = xb + (size_t)l1 * D_MODEL + kb;
            sum[rr] = 0.f; ssq[rr] = 0.f;
            #pragma unroll
            for (int i = 0; i < 4; ++i) {
                const float* p = (i < 2) ? (p0 + i * 256) : (p1 + (i - 2) * 256);
                v[rr][i] = *(const f32x4*)p;
                #pragma unroll
                for (int q = 0; q < 4; ++q) {
                    sum[rr] += v[rr][i][q];
                    ssq[rr] += v[rr][i][q] * v[rr][i][q];
                }
            }
        }

        #pragma unroll
        for (int off = 32; off >= 1; off >>= 1) {
            #pragma unroll
            for (int rr = 0; rr < 4; ++rr) {
                sum[rr] += __shfl_xor(sum[rr], off);
                ssq[rr] += __shfl_xor(ssq[rr], off);
            }
        }

        float mu[4], rs[4];
        #pragma unroll
        for (int rr = 0; rr < 4; ++rr) {
            mu[rr] = sum[rr] * (1.f / 1024.f);
            const float var = ssq[rr] * (1.f / 1024.f) - mu[rr] * mu[rr];
            rs[rr] = rsqrtf(var + 1e-5f);
        }

        #pragma unroll
        for (int i = 0; i < 4; ++i) {
            const int k = i * 256 + kb;
            const f32x4 w4 = *(const f32x4*)(norm_w + k);
            const f32x4 b4 = *(const f32x4*)(norm_b + k);
            const int kc = k >> 3;           // i*32 + (lane>>1)
            const int j = k & 7;             // (lane&1)*4
            const int rot = kc & 31;
            #pragma unroll
            for (int rr = 0; rr < 4; ++rr) {
                const int r = wave * 4 + rr;
                bf16x4 o;
                #pragma unroll
                for (int q = 0; q < 4; ++q)
                    o[q] = (__bf16)((v[rr][i][q] - mu[rr]) * rs[rr] * w4[q] + b4[q]);
                const int row = r ^ rot;     // swizzle
                *(bf16x4*)&Alds[(kc * 32 + row) * 8 + j] = o;
            }
        }
    }
    __syncthreads();

    // ---------------- Phase 2: bf16 MFMA GEMM (32 x 512 per block) ----------
    // 8 waves x 64 output cols; B in fragment order -> 1 KiB contiguous/load,
    // explicit 1-deep register prefetch to hide L2 latency.
    const int col = lane & 15;
    const int quad = lane >> 4;
    const int n0 = wave * 64;

    f32x4 acc[2][4] = {};
    // chunk base for this wave: n_tiles wave*4 .. wave*4+3
    const __bf16* bp = Bp + ((size_t)(wave * 4) * 32 + 0) * 512 + lane * 8;
    // load for (nt, kk): bp + (nt*32 + kk)*512

    bf16x8 bcur[4];
    #pragma unroll
    for (int nt = 0; nt < 4; ++nt)
        bcur[nt] = *(const bf16x8*)(bp + (size_t)nt * (32 * 512));

    #pragma unroll 2
    for (int kk = 0; kk < 31; ++kk) {
        bf16x8 bnext[4];
        #pragma unroll
        for (int nt = 0; nt < 4; ++nt)
            bnext[nt] = *(const bf16x8*)(bp + (size_t)(nt * 32 + kk + 1) * 512);

        const int kc = kk * 4 + quad;
        const int rot = kc & 31;
        bf16x8 a0 = *(const bf16x8*)&Alds[(kc * 32 + (col ^ rot)) * 8];
        bf16x8 a1 = *(const bf16x8*)&Alds[(kc * 32 + ((16 + col) ^ rot)) * 8];
        #pragma unroll
        for (int nt = 0; nt < 4; ++nt) {
            acc[0][nt] = __builtin_amdgcn_mfma_f32_16x16x32_bf16(a0, bcur[nt], acc[0][nt], 0, 0, 0);
            acc[1][nt] = __builtin_amdgcn_mfma_f32_16x16x32_bf16(a1, bcur[nt], acc[1][nt], 0, 0, 0);
        }
        #pragma unroll
        for (int nt = 0; nt < 4; ++nt)
            bcur[nt] = bnext[nt];
    }
    {   // last k-step (kk = 31), no prefetch
        const int kc = 31 * 4 + quad;
        const int rot = kc & 31;
        bf16x8 a0 = *(const bf16x8*)&Alds[(kc * 32 + (col ^ rot)) * 8];
        bf16x8 a1 = *(const bf16x8*)&Alds[(kc * 32 + ((16 + col) ^ rot)) * 8];
        #pragma unroll
        for (int nt = 0; nt < 4; ++nt) {
            acc[0][nt] = __builtin_amdgcn_mfma_f32_16x16x32_bf16(a0, bcur[nt], acc[0][nt], 0, 0, 0);
            acc[1][nt] = __builtin_amdgcn_mfma_f32_16x16x32_bf16(a1, bcur[nt], acc[1][nt], 0, 0, 0);
        }
    }

    // ---------------- Epilogue: + lin_b, plain fp32 store (L2-coalesced) ----
    #pragma unroll
    for (int nt = 0; nt < 4; ++nt) {
        const int n = n0 + nt * 16 + col;
        const float bias = lin_b[n];
        #pragma unroll
        for (int mt = 0; mt < 2; ++mt) {
            const int row = g0 + mt * 16 + quad * 4;
            #pragma unroll
            for (int rg = 0; rg < 4; ++rg) {
                out[(size_t)(row + rg) * NDIM + n] = acc[mt][nt][rg] + bias;
            }
        }
    }
}

extern "C" void kernel_launch(void* const* d_in, const int* in_sizes, int n_in,
                              void* d_out, int out_size, void* d_ws, size_t ws_size,
                              hipStream_t stream) {
    const float* x      = (const float*)d_in[0];
    const float* norm_w = (const float*)d_in[1];
    const float* norm_b = (const float*)d_in[2];
    const float* lin_w  = (const float*)d_in[3];
    const float* lin_b  = (const float*)d_in[4];
    float* out = (float*)d_out;
    __bf16* Bp = (__bf16*)d_ws;   // 512*1024*2 = 1 MiB, fragment order

    prep_b_kernel<<<256, 256, 0, stream>>>(lin_w, Bp);
    fused_ln_gemm_kernel<<<M_ROWS / BM, 512, 0, stream>>>(x, norm_w, norm_b, Bp, lin_b, out);
}